// Round 4
// baseline (306.570 us; speedup 1.0000x reference)
//
#include <hip/hip_runtime.h>
#include <cstddef>

#define BT   8192
#define HD   2048
#define NS   32
#define RDIM 16
#define AD   32
#define CAP  1024

// ---------------- workspace layout (offsets in bytes) ----------------
// 0        : int   cnt[64]                      (slot*32+schema)
// 256      : int   tok_list[64][CAP]
// 262400   : float cf_list[64][CAP]
// 524544   : float aw[32]  (pad to 128)
// 524672   : float4 rec[BT]   {i1,i2,c1,c2}
// 655744   : float UT[32][16][2048]
// 4850048  : float y_ws[64][CAP][16]

__device__ __forceinline__ float dot4(const float4 a, const float4 b) {
    return a.x * b.x + a.y * b.y + a.z * b.z + a.w * b.w;
}
__device__ __forceinline__ void fma4(float4& o, const float a, const float4 b) {
    o.x += a * b.x; o.y += a * b.y; o.z += a * b.z; o.w += a * b.w;
}

// pair-adjacent butterfly: reduces vals[64] (indexed m) across 64 lanes;
// afterwards lane L holds full sum of value m=L in vals[0]. (R3-proven)
__device__ __forceinline__ void reduce64(float* vals, const int lane) {
    #pragma unroll
    for (int st = 0; st < 6; ++st) {
        const int d = 1 << st;
        const bool up = (lane & d) != 0;
        const int half = 32 >> st;
        #pragma unroll
        for (int i = 0; i < half; ++i) {
            const float lo = vals[2 * i], hi = vals[2 * i + 1];
            const float keep = up ? hi : lo, send = up ? lo : hi;
            vals[i] = keep + __shfl_xor(send, d, 64);
        }
    }
}

// ---------------- prep: transpose U -> UT[s][k][j]; compute aw[s] ----------------
__global__ __launch_bounds__(256) void k_prep(const float* __restrict__ U,
                                              const float* __restrict__ attr,
                                              const float* __restrict__ Wa,
                                              float* __restrict__ UT,
                                              float* __restrict__ aw) {
    const int bx = blockIdx.x;
    if (bx == NS * 8) {
        if (threadIdx.x < NS) {
            float d = 0.f;
            #pragma unroll 1
            for (int k = 0; k < AD; ++k) d += attr[threadIdx.x * AD + k] * Wa[k];
            aw[threadIdx.x] = 1.f / (1.f + __expf(-d));
        }
        return;
    }
    const int s = bx >> 3, jc = bx & 7;
    const int j = jc * 256 + threadIdx.x;
    const float4* Up = (const float4*)(U + ((size_t)s * HD + j) * RDIM);
    const float4 a = Up[0], b = Up[1], c = Up[2], d = Up[3];
    float* Tp = UT + (size_t)s * RDIM * HD + j;
    Tp[0]     = a.x; Tp[HD]    = a.y; Tp[2*HD]  = a.z; Tp[3*HD]  = a.w;
    Tp[4*HD]  = b.x; Tp[5*HD]  = b.y; Tp[6*HD]  = b.z; Tp[7*HD]  = b.w;
    Tp[8*HD]  = c.x; Tp[9*HD]  = c.y; Tp[10*HD] = c.z; Tp[11*HD] = c.w;
    Tp[12*HD] = d.x; Tp[13*HD] = d.y; Tp[14*HD] = d.z; Tp[15*HD] = d.w;
}

// ---------------- router: no atomics, per-token record ----------------
// 1024 blocks x 8 tokens; wave w -> schemas w*8..w*8+7, single pass.
// h AND Wr register-double-buffered across 256-wide K chunks; butterfly reduce.
__global__ __launch_bounds__(256) void k_router(
    const float* __restrict__ h, const float* __restrict__ Wr,
    const float* __restrict__ aw, float4* __restrict__ rec)
{
    __shared__ float sc_s[8][NS + 1];
    __shared__ float aw_s[NS];
    const int tid = threadIdx.x, w = tid >> 6, lane = tid & 63;
    const int t0 = blockIdx.x * 8;
    if (tid < NS) aw_s[tid] = aw[tid];
    const int sb = w * 8;

    float vals[64];
    #pragma unroll
    for (int m = 0; m < 64; ++m) vals[m] = 0.f;

    float4 hA[8], hB[8], wA[8], wB[8];
    #pragma unroll
    for (int t = 0; t < 8; ++t)
        hA[t] = *(const float4*)(h + (size_t)(t0 + t) * HD + lane * 4);
    #pragma unroll
    for (int sl = 0; sl < 8; ++sl)
        wA[sl] = *(const float4*)(Wr + (size_t)(sb + sl) * HD + lane * 4);

    #pragma unroll 1
    for (int c = 0; c < 8; ++c) {
        if (c < 7) {
            #pragma unroll
            for (int t = 0; t < 8; ++t)
                hB[t] = *(const float4*)(h + (size_t)(t0 + t) * HD + (c + 1) * 256 + lane * 4);
            #pragma unroll
            for (int sl = 0; sl < 8; ++sl)
                wB[sl] = *(const float4*)(Wr + (size_t)(sb + sl) * HD + (c + 1) * 256 + lane * 4);
        }
        #pragma unroll
        for (int sl = 0; sl < 8; ++sl)
            #pragma unroll
            for (int t = 0; t < 8; ++t)
                vals[t * 8 + sl] += dot4(hA[t], wA[sl]);
        if (c < 7) {
            #pragma unroll
            for (int t = 0; t < 8; ++t) hA[t] = hB[t];
            #pragma unroll
            for (int sl = 0; sl < 8; ++sl) wA[sl] = wB[sl];
        }
    }

    reduce64(vals, lane);                      // lane L holds m=L (t=L>>3, s=L&7)
    sc_s[lane >> 3][sb + (lane & 7)] = vals[0];
    __syncthreads();

    if (tid < 8) {
        const int t = tid;
        float m1 = -1e30f, m2 = -1e30f;
        int i1 = 0, i2 = 0;
        #pragma unroll 1
        for (int sI = 0; sI < NS; ++sI) {   // strict > keeps lowest index on ties (lax.top_k)
            const float v = sc_s[t][sI];
            if (v > m1) { m2 = m1; i2 = i1; m1 = v; i1 = sI; }
            else if (v > m2) { m2 = v; i2 = sI; }
        }
        float Z = 0.f;
        #pragma unroll 1
        for (int sI = 0; sI < NS; ++sI) Z += __expf(sc_s[t][sI] - m1);
        const float e2  = __expf(m2 - m1);
        // g = softmax(sc)*mask renormed by (sum + 1e-8): G_i = e_i / (e1+e2 + 1e-8*Z)
        const float den = 1.f + e2 + 1e-8f * Z;
        const float G1 = 1.f / den, G2 = e2 / den;
        const float mult = 0.9f + 0.2f * (G1 * aw_s[i1] + G2 * aw_s[i2]);
        rec[t0 + t] = make_float4(__int_as_float(i1), __int_as_float(i2),
                                  G1 * mult, G2 * mult);
    }
}

// ---------------- build lists: one block per (slot,schema) bin ----------------
// Deterministic ballot-compaction of 8192 records; no atomics.
__global__ __launch_bounds__(256) void k_build(
    const float4* __restrict__ rec, int* __restrict__ cnt,
    int* __restrict__ tok_list, float* __restrict__ cf_list)
{
    __shared__ int wcnt[4];
    const int g = blockIdx.x, slot = g >> 5, sch = g & 31;
    const int tid = threadIdx.x, w = tid >> 6, lane = tid & 63;
    int running = 0;

    #pragma unroll 1
    for (int it = 0; it < BT / 256; ++it) {
        const int i = it * 256 + tid;
        const float4 r = rec[i];
        const int pick = __float_as_int(slot ? r.y : r.x);
        const bool m = (pick == sch);
        const unsigned long long bal = __ballot(m);
        if (lane == 0) wcnt[w] = (int)__popcll(bal);
        __syncthreads();
        int base = running;
        #pragma unroll
        for (int ww = 0; ww < 4; ++ww) if (ww < w) base += wcnt[ww];
        if (m) {
            const int pos = base + (int)__popcll(bal & ((1ull << lane) - 1));
            if (pos < CAP) {
                tok_list[g * CAP + pos] = i;
                cf_list[g * CAP + pos]  = slot ? r.w : r.z;
            }
        }
        running += wcnt[0] + wcnt[1] + wcnt[2] + wcnt[3];
        __syncthreads();
    }
    if (tid == 0) cnt[g] = running < CAP ? running : CAP;
}

// ---------------- pass A: y = cf * (h @ U[s]) ----------------
// Wave = 4 tokens, full rank; h dbuf across chunks, UT prefetched per kg-group.
__global__ __launch_bounds__(256) void k_A(
    const float* __restrict__ h, const int* __restrict__ cnt,
    const int* __restrict__ tok_list, const float* __restrict__ cf_list,
    const float* __restrict__ UT, float* __restrict__ y_ws)
{
    const int g = blockIdx.x, s = g & (NS - 1);
    int count = cnt[g]; if (count > CAP) count = CAP;
    const int tid = threadIdx.x, w = tid >> 6, lane = tid & 63;
    const float* UTs = UT + (size_t)s * RDIM * HD;

    #pragma unroll 1
    for (int ci = blockIdx.y; ci * 16 < count; ci += gridDim.y) {
        int tok[4]; float cf[4];
        #pragma unroll
        for (int r = 0; r < 4; ++r) {
            const int idx = ci * 16 + w * 4 + r;
            const bool vld = idx < count;
            int tv = vld ? tok_list[g * CAP + idx] : 0;
            tok[r] = __builtin_amdgcn_readfirstlane(tv);
            cf[r]  = vld ? cf_list[g * CAP + idx] : 0.f;
        }
        const float* hp0 = h + (size_t)tok[0] * HD;
        const float* hp1 = h + (size_t)tok[1] * HD;
        const float* hp2 = h + (size_t)tok[2] * HD;
        const float* hp3 = h + (size_t)tok[3] * HD;

        float vals[64];
        #pragma unroll
        for (int m = 0; m < 64; ++m) vals[m] = 0.f;

        float4 hA[4], hB[4], uA[4], uB[4];
        hA[0] = *(const float4*)(hp0 + lane * 4);
        hA[1] = *(const float4*)(hp1 + lane * 4);
        hA[2] = *(const float4*)(hp2 + lane * 4);
        hA[3] = *(const float4*)(hp3 + lane * 4);
        #pragma unroll
        for (int q = 0; q < 4; ++q)
            uA[q] = *(const float4*)(UTs + (size_t)q * HD + lane * 4);

        #pragma unroll 1
        for (int c = 0; c < 8; ++c) {
            const int off = c * 256 + lane * 4;
            if (c < 7) {
                hB[0] = *(const float4*)(hp0 + off + 256);
                hB[1] = *(const float4*)(hp1 + off + 256);
                hB[2] = *(const float4*)(hp2 + off + 256);
                hB[3] = *(const float4*)(hp3 + off + 256);
            }
            #pragma unroll
            for (int kg = 0; kg < 4; ++kg) {
                if (kg < 3) {
                    #pragma unroll
                    for (int q = 0; q < 4; ++q)
                        uB[q] = *(const float4*)(UTs + (size_t)((kg + 1) * 4 + q) * HD + off);
                } else if (c < 7) {
                    #pragma unroll
                    for (int q = 0; q < 4; ++q)
                        uB[q] = *(const float4*)(UTs + (size_t)q * HD + off + 256);
                }
                #pragma unroll
                for (int q = 0; q < 4; ++q) {
                    vals[0 * 16 + kg * 4 + q] += dot4(hA[0], uA[q]);
                    vals[1 * 16 + kg * 4 + q] += dot4(hA[1], uA[q]);
                    vals[2 * 16 + kg * 4 + q] += dot4(hA[2], uA[q]);
                    vals[3 * 16 + kg * 4 + q] += dot4(hA[3], uA[q]);
                }
                #pragma unroll
                for (int q = 0; q < 4; ++q) uA[q] = uB[q];
            }
            if (c < 7) {
                #pragma unroll
                for (int r = 0; r < 4; ++r) hA[r] = hB[r];
            }
        }

        reduce64(vals, lane);                 // lane L holds m=L (r=L>>4, k=L&15)
        const int rsel = lane >> 4;
        const float cfv = rsel == 0 ? cf[0] : rsel == 1 ? cf[1] : rsel == 2 ? cf[2] : cf[3];
        y_ws[(size_t)g * (CAP * 16) + (size_t)(ci * 16 + w * 4) * 16 + lane] = vals[0] * cfv;
    }
}

// ---------------- pass B: out (+)= y @ V[s] ----------------
// Wave = 4 tokens; V prefetched per kg-group; y broadcast from LDS.
// slot 0 stores (argmax covers each token once), slot 1 non-atomic RMW add.
__global__ __launch_bounds__(256) void k_B(
    const float* __restrict__ V, const int* __restrict__ cnt,
    const int* __restrict__ tok_list, const float* __restrict__ y_ws,
    float* __restrict__ out, const int slot)
{
    __shared__ __align__(16) float ylds[256];
    __shared__ int toks_s[16];
    const int gsch = blockIdx.x;
    const int g = slot * NS + gsch;
    int count = cnt[g]; if (count > CAP) count = CAP;
    const int tid = threadIdx.x, w = tid >> 6, lane = tid & 63;
    const float* Vs = V + (size_t)gsch * RDIM * HD;

    #pragma unroll 1
    for (int ci = blockIdx.y; ci * 16 < count; ci += gridDim.y) {
        __syncthreads();   // protect ylds/toks_s from previous iteration's readers
        if (tid < 16)
            toks_s[tid] = (ci * 16 + tid < count) ? tok_list[g * CAP + ci * 16 + tid] : -1;
        ylds[tid] = y_ws[(size_t)g * (CAP * 16) + (size_t)ci * 256 + tid];
        __syncthreads();

        int tok[4]; bool act[4];
        #pragma unroll
        for (int r = 0; r < 4; ++r) {
            const int tv = toks_s[w * 4 + r];
            act[r] = tv >= 0; tok[r] = act[r] ? tv : 0;
        }

        float4 vA[4], vB[4];
        #pragma unroll
        for (int q = 0; q < 4; ++q)
            vA[q] = *(const float4*)(Vs + (size_t)q * HD + lane * 4);

        #pragma unroll 1
        for (int c = 0; c < 8; ++c) {
            const int off = c * 256 + lane * 4;
            float4 ov[4];
            if (slot) {
                #pragma unroll
                for (int r = 0; r < 4; ++r)
                    if (act[r]) ov[r] = *(const float4*)(out + (size_t)tok[r] * HD + off);
            }
            float4 o[4];
            #pragma unroll
            for (int r = 0; r < 4; ++r) o[r] = make_float4(0.f, 0.f, 0.f, 0.f);

            #pragma unroll
            for (int kg = 0; kg < 4; ++kg) {
                if (kg < 3) {
                    #pragma unroll
                    for (int q = 0; q < 4; ++q)
                        vB[q] = *(const float4*)(Vs + (size_t)((kg + 1) * 4 + q) * HD + off);
                } else if (c < 7) {
                    #pragma unroll
                    for (int q = 0; q < 4; ++q)
                        vB[q] = *(const float4*)(Vs + (size_t)q * HD + off + 256);
                }
                #pragma unroll
                for (int r = 0; r < 4; ++r) {
                    const float4 yv = *(const float4*)&ylds[(w * 4 + r) * 16 + kg * 4];
                    fma4(o[r], yv.x, vA[0]); fma4(o[r], yv.y, vA[1]);
                    fma4(o[r], yv.z, vA[2]); fma4(o[r], yv.w, vA[3]);
                }
                #pragma unroll
                for (int q = 0; q < 4; ++q) vA[q] = vB[q];
            }
            #pragma unroll
            for (int r = 0; r < 4; ++r) {
                if (act[r]) {
                    float* op = out + (size_t)tok[r] * HD + off;
                    if (slot) {
                        o[r].x += ov[r].x; o[r].y += ov[r].y;
                        o[r].z += ov[r].z; o[r].w += ov[r].w;
                    }
                    *(float4*)op = o[r];
                }
            }
        }
    }
}

extern "C" void kernel_launch(void* const* d_in, const int* in_sizes, int n_in,
                              void* d_out, int out_size, void* d_ws, size_t ws_size,
                              hipStream_t stream)
{
    const float* h    = (const float*)d_in[0];
    const float* Wr   = (const float*)d_in[1];
    const float* U    = (const float*)d_in[2];
    const float* V    = (const float*)d_in[3];
    const float* attr = (const float*)d_in[4];
    const float* Wa   = (const float*)d_in[5];
    float* outp = (float*)d_out;

    char* ws = (char*)d_ws;
    int*    cnt      = (int*)ws;
    int*    tok_list = (int*)(ws + 256);
    float*  cf_list  = (float*)(ws + 262400);
    float*  aw       = (float*)(ws + 524544);
    float4* rec      = (float4*)(ws + 524672);
    float*  UT       = (float*)(ws + 655744);
    float*  y_ws     = (float*)(ws + 4850048);

    hipLaunchKernelGGL(k_prep,   dim3(NS * 8 + 1), dim3(256), 0, stream,
                       U, attr, Wa, UT, aw);
    hipLaunchKernelGGL(k_router, dim3(BT / 8),     dim3(256), 0, stream,
                       h, Wr, aw, rec);
    hipLaunchKernelGGL(k_build,  dim3(64),         dim3(256), 0, stream,
                       rec, cnt, tok_list, cf_list);
    hipLaunchKernelGGL(k_A,      dim3(64, 16),     dim3(256), 0, stream,
                       h, cnt, tok_list, cf_list, UT, y_ws);
    hipLaunchKernelGGL(k_B,      dim3(NS, 16),     dim3(256), 0, stream,
                       V, cnt, tok_list, y_ws, outp, 0);
    hipLaunchKernelGGL(k_B,      dim3(NS, 16),     dim3(256), 0, stream,
                       V, cnt, tok_list, y_ws, outp, 1);
}